// Round 7
// baseline (159.364 us; speedup 1.0000x reference)
//
#include <hip/hip_runtime.h>
#include <hip/hip_bf16.h>
#include <stdint.h>

// GAT layer, MI355X. B=32, N=512, Fin=256, F=64, H=8. fp32 in / fp32 out.
// R13 = R12 (all kernels < 40.6us fill; fit: k1~31us, k2~25-30, k0~6) + ONE
// change: k1 rebuilt with zero in-loop global loads (same proven theory as
// R12's k2 fix — the 16-row av gathers were serializing ~16 lines/instr).
//   k1 v2: grid (32,8,4), wave owns 16 rows; ALL x-fragments for K=256
//   prefetched at kernel entry (16 independent float4 = 64 VGPR, one
//   latency, hidden under WT staging), fully-unrolled static ks loop of
//   pure LDS + cvt + MFMA. acc 64->16 regs; ~116 VGPR, 2 blocks/CU.
// k0 (adj->bitmask), k2 (LDS-only attention), fallback: unchanged from R12.
// Fallback: if ws_size < 19.2MB, launch the proven R8 fused kernel.

#define ALPHA  0.2f
#define ESCALE 1.4426950408889634f   // log2(e), folded into a at stage 0

typedef __bf16 bf16x8 __attribute__((ext_vector_type(8)));
typedef __bf16 bf16x4 __attribute__((ext_vector_type(4)));
typedef float  f32x4  __attribute__((ext_vector_type(4)));

#if __has_builtin(__builtin_amdgcn_exp2f)
#define EXP2(x) __builtin_amdgcn_exp2f(x)
#else
#define EXP2(x) exp2f(x)
#endif

#define HT_STRIDE 520   // 512+8 pad: bank-spread for k2 LDS reads
#define WT_STRIDE 264   // 256+8

__device__ inline bf16x8 ld8(const float* p) {
    float4 a0 = *(const float4*)p;
    float4 a1 = *(const float4*)(p + 4);
    bf16x8 r;
    r[0]=(__bf16)a0.x; r[1]=(__bf16)a0.y; r[2]=(__bf16)a0.z; r[3]=(__bf16)a0.w;
    r[4]=(__bf16)a1.x; r[5]=(__bf16)a1.y; r[6]=(__bf16)a1.z; r[7]=(__bf16)a1.w;
    return r;
}

// ---------------- k0: adj (fp32 {0,1}) -> bitmask --------------------------
__global__ __launch_bounds__(512) void k0_mask(const float* __restrict__ adj,
                                               unsigned* __restrict__ mask) {
    const int T2 = blockIdx.x * 512 + threadIdx.x;   // 262,144 dwords = 1MB
    const int w    = T2 & 3;
    const int quad = (T2 >> 2) & 3;
    const int row  = (T2 >> 4) & 511;
    const int b    = T2 >> 13;
    const float* p = adj + ((long)b * 512 + row) * 512 + quad * 8;
    unsigned word = 0;
    #pragma unroll
    for (int k = 0; k < 4; ++k) {
        const float* qp = p + (w * 4 + k) * 32;
        float4 a0 = *(const float4*)qp;
        float4 a1 = *(const float4*)(qp + 4);
        unsigned byte =  (a0.x > 0.f ? 1u : 0u)
                      | ((a0.y > 0.f ? 1u : 0u) << 1)
                      | ((a0.z > 0.f ? 1u : 0u) << 2)
                      | ((a0.w > 0.f ? 1u : 0u) << 3)
                      | ((a1.x > 0.f ? 1u : 0u) << 4)
                      | ((a1.y > 0.f ? 1u : 0u) << 5)
                      | ((a1.z > 0.f ? 1u : 0u) << 6)
                      | ((a1.w > 0.f ? 1u : 0u) << 7);
        word |= byte << (8 * k);
    }
    mask[T2] = word;
}

// ---------------- k1 v2: zero in-loop global loads -------------------------
struct SmemK1 {
    __bf16 WT[64][WT_STRIDE];       // 33,792 B
    float  asrc[64], adst[64];      //    512 B
};                                  // 34,304 B -> 2 blocks/CU (VGPR-capped)

__global__ __launch_bounds__(512, 4) void k1_gemm(const float* __restrict__ x,
                                                  const float* __restrict__ W,
                                                  const float* __restrict__ a,
                                                  __bf16* __restrict__ hT,
                                                  float* __restrict__ ssrc,
                                                  float* __restrict__ sdst) {
    __shared__ SmemK1 sm;
    const int b = blockIdx.x, h = blockIdx.y, q4 = blockIdx.z; // XCD = b%8
    const int tid  = threadIdx.x;                // 512 thr, 8 waves
    const int wave = tid >> 6, lane = tid & 63;
    const int quad = lane >> 4, col = lane & 15;
    const int rbase = q4 * 128 + wave * 16;      // wave owns 16 rows

    // prefetch ALL x fragments for this lane's row: 16 independent float4
    // (no dependents until the MFMA loop -> all in flight concurrently)
    const float* xr = x + ((long)b * 512 + rbase + col) * 256;
    float4 raw[8][2];
    #pragma unroll
    for (int ks = 0; ks < 8; ++ks) {
        raw[ks][0] = *(const float4*)(xr + ks * 32 + quad * 8);
        raw[ks][1] = *(const float4*)(xr + ks * 32 + quad * 8 + 4);
    }

    // stage 0: a * log2e -> LDS; W head-slice fp32->bf16 -> LDS
    if (tid < 128) {
        float v = a[h * 128 + tid] * ESCALE;
        if (tid < 64) sm.asrc[tid] = v; else sm.adst[tid - 64] = v;
    }
    {
        int c = tid & 63, k0 = tid >> 6;
        #pragma unroll 4
        for (int t = 0; t < 32; ++t)
            sm.WT[c][k0 + t * 8] = (__bf16)W[(long)(k0 + t * 8) * 512 + h * 64 + c];
    }
    __syncthreads();                             // only barrier in k1

    // MFMA loop: pure LDS + cvt + MFMA (static indices, fully unrolled)
    f32x4 acc[4] = {};
    #pragma unroll
    for (int ks = 0; ks < 8; ++ks) {             // K = 256
        const int k0 = ks * 32 + quad * 8;
        bf16x8 bv[4];
        #pragma unroll
        for (int nt = 0; nt < 4; ++nt)
            bv[nt] = *(const bf16x8*)(&sm.WT[nt * 16 + col][k0]);
        bf16x8 av;
        av[0]=(__bf16)raw[ks][0].x; av[1]=(__bf16)raw[ks][0].y;
        av[2]=(__bf16)raw[ks][0].z; av[3]=(__bf16)raw[ks][0].w;
        av[4]=(__bf16)raw[ks][1].x; av[5]=(__bf16)raw[ks][1].y;
        av[6]=(__bf16)raw[ks][1].z; av[7]=(__bf16)raw[ks][1].w;
        #pragma unroll
        for (int nt = 0; nt < 4; ++nt)
            acc[nt] = __builtin_amdgcn_mfma_f32_16x16x32_bf16(av, bv[nt], acc[nt], 0, 0, 0);
    }

    // write hT[f][j] bf16 to ws (stride 520): f = nt*16+col, j = rbase+quad*4+r
    const long bh = (long)b * 8 + h;
    {
        #pragma unroll
        for (int nt = 0; nt < 4; ++nt) {
            int f = nt * 16 + col;
            int j = rbase + quad * 4;
            bf16x4 pk = { (__bf16)acc[nt][0], (__bf16)acc[nt][1],
                          (__bf16)acc[nt][2], (__bf16)acc[nt][3] };
            *(bf16x4*)(hT + (bh * 64 + f) * HT_STRIDE + j) = pk;
        }
    }

    // scores from fp32 fragments: s[j] = sum_f h[j][f]*a[f]
    {
        float asr[4], adr[4];
        #pragma unroll
        for (int nt = 0; nt < 4; ++nt) {
            asr[nt] = sm.asrc[nt * 16 + col];
            adr[nt] = sm.adst[nt * 16 + col];
        }
        #pragma unroll
        for (int r = 0; r < 4; ++r) {
            float ps = 0.f, pd = 0.f;
            #pragma unroll
            for (int nt = 0; nt < 4; ++nt) {
                ps += acc[nt][r] * asr[nt];
                pd += acc[nt][r] * adr[nt];
            }
            #pragma unroll
            for (int m = 1; m <= 8; m <<= 1) {   // stays within quad
                ps += __shfl_xor(ps, m, 64);
                pd += __shfl_xor(pd, m, 64);
            }
            if (col == 0) {
                int j = rbase + quad * 4 + r;
                ssrc[bh * 512 + j] = ps;
                sdst[bh * 512 + j] = pd;
            }
        }
    }
}

// ---------------- k2: stage 3, all operands LDS/registers ------------------
struct SmemK2 {
    __bf16 hT[64][HT_STRIDE];       // 66,560 B (staged linearly incl. pads)
    float  sds[512];                //  2,048 B
};                                  // 68,608 B -> 2 blocks/CU

__global__ __launch_bounds__(512, 4) void k2_attn(const uint4* __restrict__ mask,
                                                  const __bf16* __restrict__ hT,
                                                  const float* __restrict__ ssrc,
                                                  const float* __restrict__ sdst,
                                                  float* __restrict__ out) {
    __shared__ SmemK2 sm;
    const int b = blockIdx.x, h = blockIdx.y, q = blockIdx.z;
    const int tid  = threadIdx.x;                // 512 thr, 8 waves
    const int wave = tid >> 6, lane = tid & 63;
    const int quad = lane >> 4, col = lane & 15;
    const long bh = (long)b * 8 + h;
    const int rowbase = q * 256 + wave * 32;     // wave owns 32 rows

    // stage hT(b,h): 66,560 B = 4160 x 16B, linear coalesced copy
    {
        const uint4* src = (const uint4*)(hT + bh * 64 * HT_STRIDE);
        uint4* dst = (uint4*)&sm.hT[0][0];
        #pragma unroll
        for (int t = 0; t < 8; ++t)
            dst[t * 512 + tid] = src[t * 512 + tid];
        if (tid < 64) dst[4096 + tid] = src[4096 + tid];
    }
    sm.sds[tid] = sdst[bh * 512 + tid];

    float si[2]; uint4 mk[2];                    // mask: 16B/lane, coalesced
    #pragma unroll
    for (int it = 0; it < 2; ++it) {
        int i = rowbase + it * 16 + col;         // A-row m = lane&15
        si[it] = ssrc[bh * 512 + i];
        mk[it] = mask[((long)b * 512 + i) * 4 + quad];
    }
    __syncthreads();                             // only barrier in k2

    bf16x8 ones;
    #pragma unroll
    for (int u = 0; u < 8; ++u) ones[u] = (__bf16)1.0f;

    f32x4 acc[2][4] = {};
    f32x4 accs[2]   = {};                        // row sums via P@ones

    #pragma unroll
    for (int ks = 0; ks < 16; ++ks) {            // K = 512; zero global/barrier
        const int j0 = ks * 32 + quad * 8;
        f32x4 s0 = *(const f32x4*)&sm.sds[j0];
        f32x4 s1 = *(const f32x4*)&sm.sds[j0 + 4];
        float sd[8] = {s0[0],s0[1],s0[2],s0[3],s1[0],s1[1],s1[2],s1[3]};
        unsigned mb[2];
        #pragma unroll
        for (int it = 0; it < 2; ++it) {         // ks static -> folds
            unsigned wrd = (ks < 4) ? mk[it].x : (ks < 8) ? mk[it].y
                         : (ks < 12) ? mk[it].z : mk[it].w;
            mb[it] = (wrd >> ((ks & 3) * 8)) & 0xFFu;
        }
        bf16x8 P[2];
        #pragma unroll
        for (int it = 0; it < 2; ++it)
            #pragma unroll
            for (int u = 0; u < 8; ++u) {
                float e = si[it] + sd[u];        // pre-scaled by log2e
                float l = fmaxf(e, ALPHA * e);   // lrelu
                float xv = EXP2(l);
                P[it][u] = (__bf16)(((mb[it] >> u) & 1u) ? xv : 0.0f);
            }
        bf16x8 bv[4];
        #pragma unroll
        for (int nt = 0; nt < 4; ++nt)
            bv[nt] = *(const bf16x8*)(&sm.hT[nt * 16 + col][j0]);
        #pragma unroll
        for (int it = 0; it < 2; ++it) {
            #pragma unroll
            for (int nt = 0; nt < 4; ++nt)
                acc[it][nt] = __builtin_amdgcn_mfma_f32_16x16x32_bf16(P[it], bv[nt], acc[it][nt], 0, 0, 0);
            accs[it] = __builtin_amdgcn_mfma_f32_16x16x32_bf16(P[it], ones, accs[it], 0, 0, 0);
        }
    }
    // epilogue: accs rows (quad*4+r) align with acc rows
    #pragma unroll
    for (int it = 0; it < 2; ++it)
        #pragma unroll
        for (int r = 0; r < 4; ++r) {
            float s = accs[it][r];
            float inv = (s > 0.f) ? 1.0f / s : 0.f;
            int i = rowbase + it * 16 + quad * 4 + r;
            float* orow = out + ((long)b * 512 + i) * 512 + h * 64;
            #pragma unroll
            for (int nt = 0; nt < 4; ++nt)
                orow[nt * 16 + col] = acc[it][nt][r] * inv;
        }
}

// ---------------- fallback: R8 fused kernel (proven) -----------------------
struct SmemF {
    __bf16 hT[64][HT_STRIDE];
    __bf16 WT[64][WT_STRIDE];
    float  ssrc[512], sdst[512];
    float  asrc[64], adst[64];
};

__global__ __launch_bounds__(1024, 4) void k_gat_fused(const float* __restrict__ x,
                                                       const float* __restrict__ adj,
                                                       const float* __restrict__ W,
                                                       const float* __restrict__ a,
                                                       float* __restrict__ out) {
    __shared__ SmemF sm;
    const int b = blockIdx.x, h = blockIdx.y;
    const int tid  = threadIdx.x;
    const int wave = tid >> 6, lane = tid & 63;
    const int quad = lane >> 4, col = lane & 15;

    if (tid < 128) {
        float v = a[h * 128 + tid] * ESCALE;
        if (tid < 64) sm.asrc[tid] = v; else sm.adst[tid - 64] = v;
    }
    {
        int c = tid & 63, k0 = tid >> 6;
        #pragma unroll 4
        for (int t = 0; t < 16; ++t)
            sm.WT[c][k0 + t * 16] = (__bf16)W[(long)(k0 + t * 16) * 512 + h * 64 + c];
    }
    __syncthreads();
    {
        const float* xb = x + (long)b * 512 * 256;
        f32x4 acc[2][4] = {};
        for (int ks = 0; ks < 8; ++ks) {
            int k0 = ks * 32 + quad * 8;
            bf16x8 av[2], bv[4];
            #pragma unroll
            for (int it = 0; it < 2; ++it)
                av[it] = ld8(xb + (long)(wave * 32 + it * 16 + col) * 256 + k0);
            #pragma unroll
            for (int nt = 0; nt < 4; ++nt)
                bv[nt] = *(const bf16x8*)(&sm.WT[nt * 16 + col][k0]);
            #pragma unroll
            for (int it = 0; it < 2; ++it)
                #pragma unroll
                for (int nt = 0; nt < 4; ++nt)
                    acc[it][nt] = __builtin_amdgcn_mfma_f32_16x16x32_bf16(av[it], bv[nt], acc[it][nt], 0, 0, 0);
        }
        #pragma unroll
        for (int it = 0; it < 2; ++it)
            #pragma unroll
            for (int nt = 0; nt < 4; ++nt) {
                int f = nt * 16 + col;
                int j = wave * 32 + it * 16 + quad * 4;
                bf16x4 pk = { (__bf16)acc[it][nt][0], (__bf16)acc[it][nt][1],
                              (__bf16)acc[it][nt][2], (__bf16)acc[it][nt][3] };
                *(bf16x4*)(&sm.hT[f][j]) = pk;
            }
    }
    __syncthreads();
    {
        int j = tid & 511;
        float s = 0.f;
        if (tid < 512) {
            #pragma unroll 8
            for (int f = 0; f < 64; ++f) s += (float)sm.hT[f][j] * sm.asrc[f];
            sm.ssrc[j] = s;
        } else {
            #pragma unroll 8
            for (int f = 0; f < 64; ++f) s += (float)sm.hT[f][j] * sm.adst[f];
            sm.sdst[j] = s;
        }
    }
    __syncthreads();
    {
        float si[2];
        const float* arow[2];
        #pragma unroll
        for (int it = 0; it < 2; ++it) {
            int i = wave * 32 + it * 16 + col;
            si[it]   = sm.ssrc[i];
            arow[it] = adj + ((long)b * 512 + i) * 512;
        }
        bf16x8 ones;
        #pragma unroll
        for (int u = 0; u < 8; ++u) ones[u] = (__bf16)1.0f;
        f32x4 acc[2][4] = {};
        f32x4 accs[2]   = {};
        float4 pa0[2], pa1[2];
        #pragma unroll
        for (int it = 0; it < 2; ++it) {
            pa0[it] = *(const float4*)(arow[it] + quad * 8);
            pa1[it] = *(const float4*)(arow[it] + quad * 8 + 4);
        }
        for (int ks = 0; ks < 16; ++ks) {
            int j0 = ks * 32 + quad * 8;
            f32x4 s0 = *(const f32x4*)&sm.sdst[j0];
            f32x4 s1 = *(const f32x4*)&sm.sdst[j0 + 4];
            float sd[8] = {s0[0],s0[1],s0[2],s0[3],s1[0],s1[1],s1[2],s1[3]};
            float am[2][8];
            #pragma unroll
            for (int it = 0; it < 2; ++it) {
                am[it][0]=pa0[it].x; am[it][1]=pa0[it].y;
                am[it][2]=pa0[it].z; am[it][3]=pa0[it].w;
                am[it][4]=pa1[it].x; am[it][5]=pa1[it].y;
                am[it][6]=pa1[it].z; am[it][7]=pa1[it].w;
            }
            if (ks < 15) {
                #pragma unroll
                for (int it = 0; it < 2; ++it) {
                    pa0[it] = *(const float4*)(arow[it] + j0 + 32);
                    pa1[it] = *(const float4*)(arow[it] + j0 + 36);
                }
            }
            bf16x8 P[2];
            #pragma unroll
            for (int it = 0; it < 2; ++it)
                #pragma unroll
                for (int u = 0; u < 8; ++u) {
                    float e = si[it] + sd[u];
                    float l = fmaxf(e, ALPHA * e);
                    float p = am[it][u] * EXP2(l);
                    P[it][u] = (__bf16)p;
                }
            bf16x8 bv[4];
            #pragma unroll
            for (int nt = 0; nt < 4; ++nt)
                bv[nt] = *(const bf16x8*)(&sm.hT[nt * 16 + col][j0]);
            #pragma unroll
            for (int it = 0; it < 2; ++it) {
                #pragma unroll
                for (int nt = 0; nt < 4; ++nt)
                    acc[it][nt] = __builtin_amdgcn_mfma_f32_16x16x32_bf16(P[it], bv[nt], acc[it][nt], 0, 0, 0);
                accs[it] = __builtin_amdgcn_mfma_f32_16x16x32_bf16(P[it], ones, accs[it], 0, 0, 0);
            }
        }
        #pragma unroll
        for (int it = 0; it < 2; ++it)
            #pragma unroll
            for (int r = 0; r < 4; ++r) {
                float s = accs[it][r];
                float inv = (s > 0.f) ? 1.0f / s : 0.f;
                int i = wave * 32 + it * 16 + quad * 4 + r;
                float* orow = out + ((long)b * 512 + i) * 512 + h * 64;
                #pragma unroll
                for (int nt = 0; nt < 4; ++nt)
                    orow[nt * 16 + col] = acc[it][nt][r] * inv;
            }
    }
}

// ---------------- launch ---------------------------------------------------
extern "C" void kernel_launch(void* const* d_in, const int* in_sizes, int n_in,
                              void* d_out, int out_size, void* d_ws, size_t ws_size,
                              hipStream_t stream) {
    const float* x   = (const float*)d_in[0];   // (32,512,256)
    const float* adj = (const float*)d_in[1];   // (32,512,512), {0,1}
    const float* W   = (const float*)d_in[2];   // (256,512)
    const float* a   = (const float*)d_in[3];   // (8,128)
    float* out = (float*)d_out;                 // (32,512,512)

    const size_t HT_BYTES   = 256ull * 64 * HT_STRIDE * 2;   // 17,039,360
    const size_t SC_BYTES   = 32ull * 8 * 512 * 4;           //    524,288
    const size_t MASK_BYTES = 32ull * 512 * 64;              //  1,048,576
    const size_t NEED = HT_BYTES + 2 * SC_BYTES + MASK_BYTES;// 19,136,512

    if (d_ws && ws_size >= NEED) {
        __bf16* hT   = (__bf16*)d_ws;
        float* ssrc  = (float*)((char*)d_ws + HT_BYTES);
        float* sdst  = ssrc + 32 * 8 * 512;
        unsigned* mk = (unsigned*)((char*)d_ws + HT_BYTES + 2 * SC_BYTES);
        k0_mask<<<512, 512, 0, stream>>>(adj, mk);
        k1_gemm<<<dim3(32, 8, 4), 512, 0, stream>>>(x, W, a, hT, ssrc, sdst);
        k2_attn<<<dim3(32, 8, 2), 512, 0, stream>>>((const uint4*)mk, hT, ssrc, sdst, out);
    } else {
        k_gat_fused<<<dim3(32, 8), 1024, 0, stream>>>(x, adj, W, a, out);
    }
}

// Round 9
// 148.150 us; speedup vs baseline: 1.0757x; 1.0757x over previous
//
#include <hip/hip_runtime.h>
#include <hip/hip_bf16.h>
#include <stdint.h>

// GAT layer, MI355X. B=32, N=512, Fin=256, F=64, H=8. fp32 in / fp32 out.
// R14 (resubmit; prior round was an infra failure, kernel never ran):
// k1 rebuilt on pre-formatted layouts (R13 post-mortem: VGPR=52 proved
// the compiler sank the register prefetch; WT stage writes were 8-way bank
// conflicts, 7.86M cycles). The only approach that has worked (R12 k2, -45us)
// is layout surgery so the hot loop has NO gathers / NO cvt / NO conflicts:
//   k0_all: one merged streaming pass: x -> xbf[b][kc][row][64k] bf16
//           (kc-blocked: k1 K-steps become contiguous 64KB slabs);
//           W -> Wbf[n][k] bf16 (LDS tile transpose); adj -> bitmask.
//   k1 v4: grid (32,8,2), 512thr, LDS 66KB (2 blocks/CU). Stage Wt+Xt with
//          linear coalesced uint4 copies, XOR-swizzle (granule ^= row&7) on
//          the WRITE; inner loop = ds_read_b128 (2-way, free) + MFMA only.
//          Xt single-buffered across 4 K-chunks (8 barriers).
//   k2 / fallback: unchanged from R12 (attribution).
// Fallback: if ws_size < 27.8MB, launch the proven R8 fused kernel.

#define ALPHA  0.2f
#define ESCALE 1.4426950408889634f   // log2(e), folded into a at stage 0

typedef __bf16 bf16x8 __attribute__((ext_vector_type(8)));
typedef __bf16 bf16x4 __attribute__((ext_vector_type(4)));
typedef float  f32x4  __attribute__((ext_vector_type(4)));

#if __has_builtin(__builtin_amdgcn_exp2f)
#define EXP2(x) __builtin_amdgcn_exp2f(x)
#else
#define EXP2(x) exp2f(x)
#endif

#define HT_STRIDE 520   // 512+8 pad: bank-spread for k2 LDS reads
#define WT_STRIDE 264   // fused-fallback only

__device__ inline bf16x8 ld8(const float* p) {
    float4 a0 = *(const float4*)p;
    float4 a1 = *(const float4*)(p + 4);
    bf16x8 r;
    r[0]=(__bf16)a0.x; r[1]=(__bf16)a0.y; r[2]=(__bf16)a0.z; r[3]=(__bf16)a0.w;
    r[4]=(__bf16)a1.x; r[5]=(__bf16)a1.y; r[6]=(__bf16)a1.z; r[7]=(__bf16)a1.w;
    return r;
}

// ---------------- k0_all: pre-format pass ----------------------------------
// blocks 0..1023   : x fp32 -> xbf[b][kc][row][64] bf16 (kc-blocked)
// blocks 1024..1055: W [k][512] fp32 -> Wbf[n][k] bf16 (tile transpose)
// blocks 1056..1567: adj fp32 {0,1} -> bitmask [b][row][quad][16B]
__global__ __launch_bounds__(512) void k0_all(const float* __restrict__ x,
                                              const float* __restrict__ W,
                                              const float* __restrict__ adj,
                                              __bf16* __restrict__ xbf,
                                              __bf16* __restrict__ Wbf,
                                              unsigned* __restrict__ mask) {
    __shared__ float tile[64][65];               // W-transpose tile (else unused)
    const int blk = blockIdx.x, tid = threadIdx.x;
    if (blk < 1024) {
        // one 16B-out chunk per thread: c decomposes as [b][kc][r][s]
        long c = (long)blk * 512 + tid;          // 0..524287
        int s  = (int)(c & 7);
        int r  = (int)((c >> 3) & 511);
        int kc = (int)((c >> 12) & 3);
        int b  = (int)(c >> 14);
        const float* src = x + (((long)b * 512 + r) * 256 + kc * 64 + s * 8);
        float4 a0 = *(const float4*)src;
        float4 a1 = *(const float4*)(src + 4);
        bf16x8 o;
        o[0]=(__bf16)a0.x; o[1]=(__bf16)a0.y; o[2]=(__bf16)a0.z; o[3]=(__bf16)a0.w;
        o[4]=(__bf16)a1.x; o[5]=(__bf16)a1.y; o[6]=(__bf16)a1.z; o[7]=(__bf16)a1.w;
        *(bf16x8*)(xbf + c * 8) = o;
    } else if (blk < 1056) {
        int bi = blk - 1024;                     // 0..31
        int kt = bi & 3, ft = bi >> 2;           // 64k x 64n tile
        int ff = tid & 63;
        #pragma unroll
        for (int i = 0; i < 8; ++i) {
            int kk = (tid >> 6) + i * 8;
            tile[kk][ff] = W[(long)(kt * 64 + kk) * 512 + ft * 64 + ff];
        }
        __syncthreads();
        int kk2 = tid & 63;
        #pragma unroll
        for (int i = 0; i < 8; ++i) {
            int ff2 = (tid >> 6) + i * 8;
            Wbf[(long)(ft * 64 + ff2) * 256 + kt * 64 + kk2] = (__bf16)tile[kk2][ff2];
        }
    } else {
        const int T2 = (blk - 1056) * 512 + tid; // 262,144 dwords = 1MB
        const int w    = T2 & 3;
        const int quad = (T2 >> 2) & 3;
        const int row  = (T2 >> 4) & 511;
        const int b    = T2 >> 13;
        const float* p = adj + ((long)b * 512 + row) * 512 + quad * 8;
        unsigned word = 0;
        #pragma unroll
        for (int k = 0; k < 4; ++k) {
            const float* qp = p + (w * 4 + k) * 32;
            float4 a0 = *(const float4*)qp;
            float4 a1 = *(const float4*)(qp + 4);
            unsigned byte =  (a0.x > 0.f ? 1u : 0u)
                          | ((a0.y > 0.f ? 1u : 0u) << 1)
                          | ((a0.z > 0.f ? 1u : 0u) << 2)
                          | ((a0.w > 0.f ? 1u : 0u) << 3)
                          | ((a1.x > 0.f ? 1u : 0u) << 4)
                          | ((a1.y > 0.f ? 1u : 0u) << 5)
                          | ((a1.z > 0.f ? 1u : 0u) << 6)
                          | ((a1.w > 0.f ? 1u : 0u) << 7);
            word |= byte << (8 * k);
        }
        mask[T2] = word;
    }
}

// ---------------- k1 v4: LDS-only inner loop, swizzled tiles ---------------
struct SmemK1 {
    __bf16 Wt[64 * 256];            // 32,768 B: row n = 512B, granule-swizzled
    __bf16 Xt[256 * 64];            // 32,768 B: row r = 128B, granule-swizzled
    float  asrc[64], adst[64];      //    512 B
};                                  // 66,048 B -> 2 blocks/CU

__global__ __launch_bounds__(512, 4) void k1_gemm(const __bf16* __restrict__ xbf,
                                                  const __bf16* __restrict__ Wbf,
                                                  const float* __restrict__ a,
                                                  __bf16* __restrict__ hT,
                                                  float* __restrict__ ssrc,
                                                  float* __restrict__ sdst) {
    __shared__ SmemK1 sm;
    const int b = blockIdx.x, h = blockIdx.y, zz = blockIdx.z; // XCD = b%8
    const int tid  = threadIdx.x;                // 512 thr, 8 waves
    const int wave = tid >> 6, lane = tid & 63;
    const int quad = lane >> 4, col = lane & 15;
    const int row0 = zz * 256;                   // block's 256 rows

    if (tid < 128) {
        float v = a[h * 128 + tid] * ESCALE;
        if (tid < 64) sm.asrc[tid] = v; else sm.adst[tid - 64] = v;
    }
    {   // Wt stage: linear coalesced read, XOR-swz write (both-sides rule)
        const uint4* src = (const uint4*)(Wbf + (long)h * 64 * 256);
        #pragma unroll
        for (int i = 0; i < 4; ++i) {
            int c = tid + i * 512;               // 2048 x 16B chunks
            int f = c >> 5, s = c & 31;
            int sw = (s & 24) | ((s & 7) ^ (f & 7));
            *(uint4*)((char*)sm.Wt + f * 512 + sw * 16) = src[c];
        }
    }
    {   // Xt stage kc=0: contiguous 32KB slab (kc-blocked xbf)
        const uint4* src = (const uint4*)(xbf + (((long)b * 4 + 0) * 512 + row0) * 64);
        #pragma unroll
        for (int i = 0; i < 4; ++i) {
            int c = tid + i * 512;
            int r = c >> 3, s = c & 7;
            *(uint4*)((char*)sm.Xt + r * 128 + ((s ^ (r & 7)) * 16)) = src[c];
        }
    }
    __syncthreads();

    f32x4 acc[2][4] = {};
    #pragma unroll
    for (int kc = 0; kc < 4; ++kc) {             // K = 256, 4 chunks of 64
        #pragma unroll
        for (int sk = 0; sk < 2; ++sk) {         // 2 x K=32 MFMA steps
            bf16x8 av[2], bv[4];
            #pragma unroll
            for (int it = 0; it < 2; ++it) {     // A[m=col][k=quad*8+u]
                int r = wave * 32 + it * 16 + col;
                int g = (sk * 4 + quad) ^ (r & 7);
                av[it] = *(const bf16x8*)((const char*)sm.Xt + r * 128 + g * 16);
            }
            #pragma unroll
            for (int nt = 0; nt < 4; ++nt) {     // B[k][n=col]
                int n = nt * 16 + col;
                int G = kc * 8 + sk * 4 + quad;
                int Gs = (G & 24) | ((G & 7) ^ (n & 7));
                bv[nt] = *(const bf16x8*)((const char*)sm.Wt + n * 512 + Gs * 16);
            }
            #pragma unroll
            for (int it = 0; it < 2; ++it)
                #pragma unroll
                for (int nt = 0; nt < 4; ++nt)
                    acc[it][nt] = __builtin_amdgcn_mfma_f32_16x16x32_bf16(av[it], bv[nt], acc[it][nt], 0, 0, 0);
        }
        if (kc < 3) {                            // restage Xt for kc+1
            __syncthreads();
            const uint4* src = (const uint4*)(xbf + (((long)b * 4 + kc + 1) * 512 + row0) * 64);
            #pragma unroll
            for (int i = 0; i < 4; ++i) {
                int c = tid + i * 512;
                int r = c >> 3, s = c & 7;
                *(uint4*)((char*)sm.Xt + r * 128 + ((s ^ (r & 7)) * 16)) = src[c];
            }
            __syncthreads();
        }
    }

    // epilogue: hT (stride-520 ws) + scores (fp32-frag shfl-reduce) — proven
    const long bh = (long)b * 8 + h;
    {
        #pragma unroll
        for (int it = 0; it < 2; ++it)
            #pragma unroll
            for (int nt = 0; nt < 4; ++nt) {
                int f = nt * 16 + col;
                int j = row0 + wave * 32 + it * 16 + quad * 4;
                bf16x4 pk = { (__bf16)acc[it][nt][0], (__bf16)acc[it][nt][1],
                              (__bf16)acc[it][nt][2], (__bf16)acc[it][nt][3] };
                *(bf16x4*)(hT + (bh * 64 + f) * HT_STRIDE + j) = pk;
            }
    }
    {
        float asr[4], adr[4];
        #pragma unroll
        for (int nt = 0; nt < 4; ++nt) {
            asr[nt] = sm.asrc[nt * 16 + col];
            adr[nt] = sm.adst[nt * 16 + col];
        }
        #pragma unroll
        for (int it = 0; it < 2; ++it)
            #pragma unroll
            for (int r = 0; r < 4; ++r) {
                float ps = 0.f, pd = 0.f;
                #pragma unroll
                for (int nt = 0; nt < 4; ++nt) {
                    ps += acc[it][nt][r] * asr[nt];
                    pd += acc[it][nt][r] * adr[nt];
                }
                #pragma unroll
                for (int m = 1; m <= 8; m <<= 1) {   // stays within quad
                    ps += __shfl_xor(ps, m, 64);
                    pd += __shfl_xor(pd, m, 64);
                }
                if (col == 0) {
                    int j = row0 + wave * 32 + it * 16 + quad * 4 + r;
                    ssrc[bh * 512 + j] = ps;
                    sdst[bh * 512 + j] = pd;
                }
            }
    }
}

// ---------------- k2: stage 3, all operands LDS/registers (R12, proven) ----
struct SmemK2 {
    __bf16 hT[64][HT_STRIDE];       // 66,560 B (staged linearly incl. pads)
    float  sds[512];                //  2,048 B
};                                  // 68,608 B -> 2 blocks/CU

__global__ __launch_bounds__(512, 4) void k2_attn(const uint4* __restrict__ mask,
                                                  const __bf16* __restrict__ hT,
                                                  const float* __restrict__ ssrc,
                                                  const float* __restrict__ sdst,
                                                  float* __restrict__ out) {
    __shared__ SmemK2 sm;
    const int b = blockIdx.x, h = blockIdx.y, q = blockIdx.z;
    const int tid  = threadIdx.x;                // 512 thr, 8 waves
    const int wave = tid >> 6, lane = tid & 63;
    const int quad = lane >> 4, col = lane & 15;
    const long bh = (long)b * 8 + h;
    const int rowbase = q * 256 + wave * 32;     // wave owns 32 rows

    {
        const uint4* src = (const uint4*)(hT + bh * 64 * HT_STRIDE);
        uint4* dst = (uint4*)&sm.hT[0][0];
        #pragma unroll
        for (int t = 0; t < 8; ++t)
            dst[t * 512 + tid] = src[t * 512 + tid];
        if (tid < 64) dst[4096 + tid] = src[4096 + tid];
    }
    sm.sds[tid] = sdst[bh * 512 + tid];

    float si[2]; uint4 mk[2];                    // mask: 16B/lane, coalesced
    #pragma unroll
    for (int it = 0; it < 2; ++it) {
        int i = rowbase + it * 16 + col;         // A-row m = lane&15
        si[it] = ssrc[bh * 512 + i];
        mk[it] = mask[((long)b * 512 + i) * 4 + quad];
    }
    __syncthreads();                             // only barrier in k2

    bf16x8 ones;
    #pragma unroll
    for (int u = 0; u < 8; ++u) ones[u] = (__bf16)1.0f;

    f32x4 acc[2][4] = {};
    f32x4 accs[2]   = {};                        // row sums via P@ones

    #pragma unroll
    for (int ks = 0; ks < 16; ++ks) {            // K = 512; zero global/barrier
        const int j0 = ks * 32 + quad * 8;
        f32x4 s0 = *(const f32x4*)&sm.sds[j0];
        f32x4 s1 = *(const f32x4*)&sm.sds[j0 + 4];
        float sd[8] = {s0[0],s0[1],s0[2],s0[3],s1[0],s1[1],s1[2],s1[3]};
        unsigned mb[2];
        #pragma unroll
        for (int it = 0; it < 2; ++it) {         // ks static -> folds
            unsigned wrd = (ks < 4) ? mk[it].x : (ks < 8) ? mk[it].y
                         : (ks < 12) ? mk[it].z : mk[it].w;
            mb[it] = (wrd >> ((ks & 3) * 8)) & 0xFFu;
        }
        bf16x8 P[2];
        #pragma unroll
        for (int it = 0; it < 2; ++it)
            #pragma unroll
            for (int u = 0; u < 8; ++u) {
                float e = si[it] + sd[u];        // pre-scaled by log2e
                float l = fmaxf(e, ALPHA * e);   // lrelu
                float xv = EXP2(l);
                P[it][u] = (__bf16)(((mb[it] >> u) & 1u) ? xv : 0.0f);
            }
        bf16x8 bv[4];
        #pragma unroll
        for (int nt = 0; nt < 4; ++nt)
            bv[nt] = *(const bf16x8*)(&sm.hT[nt * 16 + col][j0]);
        #pragma unroll
        for (int it = 0; it < 2; ++it) {
            #pragma unroll
            for (int nt = 0; nt < 4; ++nt)
                acc[it][nt] = __builtin_amdgcn_mfma_f32_16x16x32_bf16(P[it], bv[nt], acc[it][nt], 0, 0, 0);
            accs[it] = __builtin_amdgcn_mfma_f32_16x16x32_bf16(P[it], ones, accs[it], 0, 0, 0);
        }
    }
    #pragma unroll
    for (int it = 0; it < 2; ++it)
        #pragma unroll
        for (int r = 0; r < 4; ++r) {
            float s = accs[it][r];
            float inv = (s > 0.f) ? 1.0f / s : 0.f;
            int i = rowbase + it * 16 + quad * 4 + r;
            float* orow = out + ((long)b * 512 + i) * 512 + h * 64;
            #pragma unroll
            for (int nt = 0; nt < 4; ++nt)
                orow[nt * 16 + col] = acc[it][nt][r] * inv;
        }
}

// ---------------- fallback: R8 fused kernel (proven) -----------------------
struct SmemF {
    __bf16 hT[64][HT_STRIDE];
    __bf16 WT[64][WT_STRIDE];
    float  ssrc[512], sdst[512];
    float  asrc[64], adst[64];
};

__global__ __launch_bounds__(1024, 4) void k_gat_fused(const float* __restrict__ x,
                                                       const float* __restrict__ adj,
                                                       const float* __restrict__ W,
                                                       const float* __restrict__ a,
                                                       float* __restrict__ out) {
    __shared__ SmemF sm;
    const int b = blockIdx.x, h = blockIdx.y;
    const int tid  = threadIdx.x;
    const int wave = tid >> 6, lane = tid & 63;
    const int quad = lane >> 4, col = lane & 15;

    if (tid < 128) {
        float v = a[h * 128 + tid] * ESCALE;
        if (tid < 64) sm.asrc[tid] = v; else sm.adst[tid - 64] = v;
    }
    {
        int c = tid & 63, k0 = tid >> 6;
        #pragma unroll 4
        for (int t = 0; t < 16; ++t)
            sm.WT[c][k0 + t * 16] = (__bf16)W[(long)(k0 + t * 16) * 512 + h * 64 + c];
    }
    __syncthreads();
    {
        const float* xb = x + (long)b * 512 * 256;
        f32x4 acc[2][4] = {};
        for (int ks = 0; ks < 8; ++ks) {
            int k0 = ks * 32 + quad * 8;
            bf16x8 av[2], bv[4];
            #pragma unroll
            for (int it = 0; it < 2; ++it)
                av[it] = ld8(xb + (long)(wave * 32 + it * 16 + col) * 256 + k0);
            #pragma unroll
            for (int nt = 0; nt < 4; ++nt)
                bv[nt] = *(const bf16x8*)(&sm.WT[nt * 16 + col][k0]);
            #pragma unroll
            for (int it = 0; it < 2; ++it)
                #pragma unroll
                for (int nt = 0; nt < 4; ++nt)
                    acc[it][nt] = __builtin_amdgcn_mfma_f32_16x16x32_bf16(av[it], bv[nt], acc[it][nt], 0, 0, 0);
        }
        #pragma unroll
        for (int it = 0; it < 2; ++it)
            #pragma unroll
            for (int nt = 0; nt < 4; ++nt) {
                int f = nt * 16 + col;
                int j = wave * 32 + it * 16 + quad * 4;
                bf16x4 pk = { (__bf16)acc[it][nt][0], (__bf16)acc[it][nt][1],
                              (__bf16)acc[it][nt][2], (__bf16)acc[it][nt][3] };
                *(bf16x4*)(&sm.hT[f][j]) = pk;
            }
    }
    __syncthreads();
    {
        int j = tid & 511;
        float s = 0.f;
        if (tid < 512) {
            #pragma unroll 8
            for (int f = 0; f < 64; ++f) s += (float)sm.hT[f][j] * sm.asrc[f];
            sm.ssrc[j] = s;
        } else {
            #pragma unroll 8
            for (int f = 0; f < 64; ++f) s += (float)sm.hT[f][j] * sm.adst[f];
            sm.sdst[j] = s;
        }
    }
    __syncthreads();
    {
        float si[2];
        const float* arow[2];
        #pragma unroll
        for (int it = 0; it < 2; ++it) {
            int i = wave * 32 + it * 16 + col;
            si[it]   = sm.ssrc[i];
            arow[it] = adj + ((long)b * 512 + i) * 512;
        }
        bf16x8 ones;
        #pragma unroll
        for (int u = 0; u < 8; ++u) ones[u] = (__bf16)1.0f;
        f32x4 acc[2][4] = {};
        f32x4 accs[2]   = {};
        float4 pa0[2], pa1[2];
        #pragma unroll
        for (int it = 0; it < 2; ++it) {
            pa0[it] = *(const float4*)(arow[it] + quad * 8);
            pa1[it] = *(const float4*)(arow[it] + quad * 8 + 4);
        }
        for (int ks = 0; ks < 16; ++ks) {
            int j0 = ks * 32 + quad * 8;
            f32x4 s0 = *(const f32x4*)&sm.sdst[j0];
            f32x4 s1 = *(const f32x4*)&sm.sdst[j0 + 4];
            float sd[8] = {s0[0],s0[1],s0[2],s0[3],s1[0],s1[1],s1[2],s1[3]};
            float am[2][8];
            #pragma unroll
            for (int it = 0; it < 2; ++it) {
                am[it][0]=pa0[it].x; am[it][1]=pa0[it].y;
                am[it][2]=pa0[it].z; am[it][3]=pa0[it].w;
                am[it][4]=pa1[it].x; am[it][5]=pa1[it].y;
                am[it][6]=pa1[it].z; am[it][7]=pa1[it].w;
            }
            if (ks < 15) {
                #pragma unroll
                for (int it = 0; it < 2; ++it) {
                    pa0[it] = *(const float4*)(arow[it] + j0 + 32);
                    pa1[it] = *(const float4*)(arow[it] + j0 + 36);
                }
            }
            bf16x8 P[2];
            #pragma unroll
            for (int it = 0; it < 2; ++it)
                #pragma unroll
                for (int u = 0; u < 8; ++u) {
                    float e = si[it] + sd[u];
                    float l = fmaxf(e, ALPHA * e);
                    float p = am[it][u] * EXP2(l);
                    P[it][u] = (__bf16)p;
                }
            bf16x8 bv[4];
            #pragma unroll
            for (int nt = 0; nt < 4; ++nt)
                bv[nt] = *(const bf16x8*)(&sm.hT[nt * 16 + col][j0]);
            #pragma unroll
            for (int it = 0; it < 2; ++it) {
                #pragma unroll
                for (int nt = 0; nt < 4; ++nt)
                    acc[it][nt] = __builtin_amdgcn_mfma_f32_16x16x32_bf16(P[it], bv[nt], acc[it][nt], 0, 0, 0);
                accs[it] = __builtin_amdgcn_mfma_f32_16x16x32_bf16(P[it], ones, accs[it], 0, 0, 0);
            }
        }
        #pragma unroll
        for (int it = 0; it < 2; ++it)
            #pragma unroll
            for (int r = 0; r < 4; ++r) {
                float s = accs[it][r];
                float inv = (s > 0.f) ? 1.0f / s : 0.f;
                int i = wave * 32 + it * 16 + quad * 4 + r;
                float* orow = out + ((long)b * 512 + i) * 512 + h * 64;
                #pragma unroll
                for (int nt = 0; nt < 4; ++nt)
                    orow[nt * 16 + col] = acc[it][nt][r] * inv;
            }
    }
}

// ---------------- launch ---------------------------------------------------
extern "C" void kernel_launch(void* const* d_in, const int* in_sizes, int n_in,
                              void* d_out, int out_size, void* d_ws, size_t ws_size,
                              hipStream_t stream) {
    const float* x   = (const float*)d_in[0];   // (32,512,256)
    const float* adj = (const float*)d_in[1];   // (32,512,512), {0,1}
    const float* W   = (const float*)d_in[2];   // (256,512)
    const float* a   = (const float*)d_in[3];   // (8,128)
    float* out = (float*)d_out;                 // (32,512,512)

    const size_t HT_BYTES   = 256ull * 64 * HT_STRIDE * 2;   // 17,039,360
    const size_t SC_BYTES   = 32ull * 8 * 512 * 4;           //    524,288
    const size_t MASK_BYTES = 32ull * 512 * 64;              //  1,048,576
    const size_t XBF_BYTES  = 32ull * 512 * 256 * 2;         //  8,388,608
    const size_t WBF_BYTES  = 512ull * 256 * 2;              //    262,144
    const size_t NEED = HT_BYTES + 2 * SC_BYTES + MASK_BYTES
                      + XBF_BYTES + WBF_BYTES;               // 27,787,264

    if (d_ws && ws_size >= NEED) {
        char* p = (char*)d_ws;
        __bf16* hT   = (__bf16*)p;                 p += HT_BYTES;
        float* ssrc  = (float*)p;                  p += SC_BYTES;
        float* sdst  = (float*)p;                  p += SC_BYTES;
        unsigned* mk = (unsigned*)p;               p += MASK_BYTES;
        __bf16* xbf  = (__bf16*)p;                 p += XBF_BYTES;
        __bf16* Wbf  = (__bf16*)p;
        k0_all<<<1568, 512, 0, stream>>>(x, W, adj, xbf, Wbf, mk);
        k1_gemm<<<dim3(32, 8, 2), 512, 0, stream>>>(xbf, Wbf, a, hT, ssrc, sdst);
        k2_attn<<<dim3(32, 8, 2), 512, 0, stream>>>((const uint4*)mk, hT, ssrc, sdst, out);
    } else {
        k_gat_fused<<<dim3(32, 8), 1024, 0, stream>>>(x, adj, W, a, out);
    }
}